// Round 1
// baseline (441.858 us; speedup 1.0000x reference)
//
#include <hip/hip_runtime.h>

// Haar IDWT2: inputs LL,LH,HL,HH each [B=16, C=64, H2=128, W2=128] fp32.
// Output [16, 64, 256, 256] fp32.
// out[2i  ,2j  ] = (LL+LH+HL+HH)/2
// out[2i  ,2j+1] = (LL+LH-HL-HH)/2
// out[2i+1,2j  ] = (LL-LH+HL-HH)/2
// out[2i+1,2j+1] = (LL-LH-HL+HH)/2
//
// Memory-bound: 768 MB total traffic, no reuse. One thread per input float4
// (4 coefficient columns) -> 4x dwordx4 loads, 4x dwordx4 stores.

#define H2 128
#define W2 128
#define W4 (W2 / 4)        // 32 float4 per input row
#define OUTW4 (2 * W2 / 4) // 64 float4 per output row

__global__ __launch_bounds__(256) void idwt_kernel(
    const float4* __restrict__ LL, const float4* __restrict__ LH,
    const float4* __restrict__ HL, const float4* __restrict__ HH,
    float4* __restrict__ out, int nquads) {
  int t = blockIdx.x * blockDim.x + threadIdx.x;
  if (t >= nquads) return;

  // flat input quad layout: plane-major, then i (row), then j4
  int j4 = t & (W4 - 1);
  int rest = t >> 5;            // log2(W4)=5
  int i = rest & (H2 - 1);
  int plane = rest >> 7;        // log2(H2)=7

  float4 ll = LL[t];
  float4 lh = LH[t];
  float4 hl = HL[t];
  float4 hh = HH[t];

  // butterflies, *0.5
  float4 a, b, c, d;
  a.x = (ll.x + lh.x + hl.x + hh.x) * 0.5f;
  b.x = (ll.x + lh.x - hl.x - hh.x) * 0.5f;
  c.x = (ll.x - lh.x + hl.x - hh.x) * 0.5f;
  d.x = (ll.x - lh.x - hl.x + hh.x) * 0.5f;
  a.y = (ll.y + lh.y + hl.y + hh.y) * 0.5f;
  b.y = (ll.y + lh.y - hl.y - hh.y) * 0.5f;
  c.y = (ll.y - lh.y + hl.y - hh.y) * 0.5f;
  d.y = (ll.y - lh.y - hl.y + hh.y) * 0.5f;
  a.z = (ll.z + lh.z + hl.z + hh.z) * 0.5f;
  b.z = (ll.z + lh.z - hl.z - hh.z) * 0.5f;
  c.z = (ll.z - lh.z + hl.z - hh.z) * 0.5f;
  d.z = (ll.z - lh.z - hl.z + hh.z) * 0.5f;
  a.w = (ll.w + lh.w + hl.w + hh.w) * 0.5f;
  b.w = (ll.w + lh.w - hl.w - hh.w) * 0.5f;
  c.w = (ll.w - lh.w + hl.w - hh.w) * 0.5f;
  d.w = (ll.w - lh.w - hl.w + hh.w) * 0.5f;

  // interleave into output rows 2i (a,b) and 2i+1 (c,d)
  float4 r0lo = make_float4(a.x, b.x, a.y, b.y);
  float4 r0hi = make_float4(a.z, b.z, a.w, b.w);
  float4 r1lo = make_float4(c.x, d.x, c.y, d.y);
  float4 r1hi = make_float4(c.z, d.z, c.w, d.w);

  // output quad index: plane*(2*H2*OUTW4) + (2i)*OUTW4 + 2*j4
  int oq = (plane << 14) + ((i << 1) * OUTW4) + (j4 << 1);
  out[oq] = r0lo;
  out[oq + 1] = r0hi;
  out[oq + OUTW4] = r1lo;
  out[oq + OUTW4 + 1] = r1hi;
}

extern "C" void kernel_launch(void* const* d_in, const int* in_sizes, int n_in,
                              void* d_out, int out_size, void* d_ws, size_t ws_size,
                              hipStream_t stream) {
  const float4* LL = (const float4*)d_in[0];
  const float4* LH = (const float4*)d_in[1];
  const float4* HL = (const float4*)d_in[2];
  const float4* HH = (const float4*)d_in[3];
  float4* out = (float4*)d_out;

  int nquads = in_sizes[0] / 4; // 16*64*128*128/4 = 4,194,304
  int block = 256;
  int grid = (nquads + block - 1) / block;
  idwt_kernel<<<grid, block, 0, stream>>>(LL, LH, HL, HH, out, nquads);
}

// Round 2
// 428.157 us; speedup vs baseline: 1.0320x; 1.0320x over previous
//
#include <hip/hip_runtime.h>

// Haar IDWT2: inputs LL,LH,HL,HH each [B=16, C=64, H2=128, W2=128] fp32.
// Output [16, 64, 256, 256] fp32.
//
// Work assignment chosen for PERFECT store coalescing:
//   one wave (64 lanes) == one input row (128 cols = 64 float2).
//   lane k loads float2 (input cols 2k, 2k+1) from each subband  -> dwordx2, contiguous
//   lane k stores float4 (output cols 4k..4k+3) to rows 2i and 2i+1 -> dwordx4,
//   each store instruction writes one full 1024-B output row, no holes.
// (Previous version stored 16 B/lane at 32-B stride -> 32 half-filled lines
//  per store instruction; this version is hole-free.)

#define H2 128
#define W2 128

__global__ __launch_bounds__(256) void idwt_kernel(
    const float2* __restrict__ LL, const float2* __restrict__ LH,
    const float2* __restrict__ HL, const float2* __restrict__ HH,
    float4* __restrict__ out, int npairs) {
  int t = blockIdx.x * blockDim.x + threadIdx.x;
  if (t >= npairs) return;

  // t is the flat float2 index: [plane][i][j2], j2 in [0,64)
  int j2 = t & 63;
  int rest = t >> 6;
  int i = rest & (H2 - 1);
  int plane = rest >> 7;

  float2 ll = LL[t];
  float2 lh = LH[t];
  float2 hl = HL[t];
  float2 hh = HH[t];

  // butterflies for the two columns this lane owns
  float4 r0, r1;  // r0 -> output row 2i, r1 -> output row 2i+1
  r0.x = (ll.x + lh.x + hl.x + hh.x) * 0.5f;  // a0
  r0.y = (ll.x + lh.x - hl.x - hh.x) * 0.5f;  // b0
  r1.x = (ll.x - lh.x + hl.x - hh.x) * 0.5f;  // c0
  r1.y = (ll.x - lh.x - hl.x + hh.x) * 0.5f;  // d0
  r0.z = (ll.y + lh.y + hl.y + hh.y) * 0.5f;  // a1
  r0.w = (ll.y + lh.y - hl.y - hh.y) * 0.5f;  // b1
  r1.z = (ll.y - lh.y + hl.y - hh.y) * 0.5f;  // c1
  r1.w = (ll.y - lh.y - hl.y + hh.y) * 0.5f;  // d1

  // output quad index: plane*(256 rows * 64 quads) + (2i)*64 + j2
  int oq = (plane << 14) | (i << 7) | j2;
  out[oq] = r0;        // row 2i
  out[oq + 64] = r1;   // row 2i+1
}

extern "C" void kernel_launch(void* const* d_in, const int* in_sizes, int n_in,
                              void* d_out, int out_size, void* d_ws, size_t ws_size,
                              hipStream_t stream) {
  const float2* LL = (const float2*)d_in[0];
  const float2* LH = (const float2*)d_in[1];
  const float2* HL = (const float2*)d_in[2];
  const float2* HH = (const float2*)d_in[3];
  float4* out = (float4*)d_out;

  int npairs = in_sizes[0] / 2;  // 16*64*128*128/2 = 8,388,608
  int block = 256;
  int grid = (npairs + block - 1) / block;
  idwt_kernel<<<grid, block, 0, stream>>>(LL, LH, HL, HH, out, npairs);
}